// Round 4
// baseline (682.185 us; speedup 1.0000x reference)
//
#include <hip/hip_runtime.h>

static constexpr int N_NODES = 100000;
static constexpr int N_EDGES = 3200000;
static constexpr int NC16    = N_NODES * 16;         // 1.6M
static constexpr int RB      = 128;                  // nodes per bucket
static constexpr int NB      = (N_NODES + RB - 1) / RB;   // 782 buckets
static constexpr int CAP     = 4800;                 // per-bucket cap (mean 4096, +11 sigma)
static constexpr int NPB     = 512;                  // partition blocks
static constexpr int EPB     = (N_EDGES + NPB - 1) / NPB; // 6250 edges/partition block

// ---------- small float4 helpers ----------
__device__ __forceinline__ float4 v4fma(float s, float4 w, float4 acc) {
    acc.x = fmaf(s, w.x, acc.x);
    acc.y = fmaf(s, w.y, acc.y);
    acc.z = fmaf(s, w.z, acc.z);
    acc.w = fmaf(s, w.w, acc.w);
    return acc;
}

// broadcast all 4 components from quad-lane KK (v_mov_b32 dpp quad_perm — VALU pipe)
template<int KK>
__device__ __forceinline__ float4 qbcast(float4 a) {
    constexpr int ctrl = KK * 0x55;   // quad_perm:[KK,KK,KK,KK]
    float4 r;
    r.x = __int_as_float(__builtin_amdgcn_mov_dpp(__float_as_int(a.x), ctrl, 0xF, 0xF, true));
    r.y = __int_as_float(__builtin_amdgcn_mov_dpp(__float_as_int(a.y), ctrl, 0xF, 0xF, true));
    r.z = __int_as_float(__builtin_amdgcn_mov_dpp(__float_as_int(a.z), ctrl, 0xF, 0xF, true));
    r.w = __int_as_float(__builtin_amdgcn_mov_dpp(__float_as_int(a.w), ctrl, 0xF, 0xF, true));
    return r;
}

// ew(channels of this lane) += sum over k in [4*KK, 4*KK+4) of a[k] * Wcol[k]
template<int KK>
__device__ __forceinline__ float4 ewstep(float4 a, const float4* wc, float4 ew) {
    float4 v = qbcast<KK>(a);
    ew = v4fma(v.x, wc[4*KK + 0], ew);
    ew = v4fma(v.y, wc[4*KK + 1], ew);
    ew = v4fma(v.z, wc[4*KK + 2], ew);
    ew = v4fma(v.w, wc[4*KK + 3], ew);
    return ew;
}

// Swizzled fp64 LDS accumulate of 4 channel values for (node dl, channel quad c4).
// Layout: channel c of node dl lives at word dl*16 + ((c + dl) & 15).
// Bank-pair of a double at word W is (W mod 16): the +dl rotation spreads a
// wave's lanes over all 16 bank-pairs -> conflict-free (was 16-way).
// Verified passing in rounds 2-3.
__device__ __forceinline__ void accum4(double* __restrict__ accS, int dl, int c4,
                                       double v0, double v1, double v2, double v3) {
    double* row = accS + dl * 16;
    const int pb = (c4 * 4 + dl) & 15;
    atomicAdd(row + ((pb + 0) & 15), v0);
    atomicAdd(row + ((pb + 1) & 15), v1);
    atomicAdd(row + ((pb + 2) & 15), v2);
    atomicAdd(row + ((pb + 3) & 15), v3);
}

// ---------------- zero gcount (kernel, NOT hipMemsetAsync — graph-capture-proof) ----
__global__ __launch_bounds__(256)
void k_zero(int* g) {
    int t = blockIdx.x * 256 + threadIdx.x;
    if (t < NB) g[t] = 0;
}

// ================= partition: meta-only (8B/edge scatter) =================
// Round-3 lesson: scattering 64B ew records cost 310MB of partial-line write
// traffic and 182us. Scattering only {eid, src<<7|dst&127} is 26MB.
__global__ __launch_bounds__(1024)
void k_part(const int* __restrict__ srcI, const int* __restrict__ dstI,
            int* __restrict__ gcount, int2* __restrict__ meta)
{
    __shared__ int hist[NB];
    const int tid  = threadIdx.x;
    const int e0   = blockIdx.x * EPB;
    const int ecnt = min(EPB, N_EDGES - e0);
    for (int t = tid; t < NB; t += 1024) hist[t] = 0;
    __syncthreads();
    for (int i = tid; i < ecnt; i += 1024) {
        int d = dstI[e0 + i];
        atomicAdd(&hist[d >> 7], 1);              // LDS int atomic (exact, commutative)
    }
    __syncthreads();
    for (int t = tid; t < NB; t += 1024) {
        int h = hist[t];
        hist[t] = (h > 0) ? atomicAdd(&gcount[t], h) : 0;   // one global atomic per bucket
    }
    __syncthreads();
    for (int i = tid; i < ecnt; i += 1024) {
        int e = e0 + i;
        int d = dstI[e];
        int s = srcI[e];
        int b = d >> 7;
        int pos = atomicAdd(&hist[b], 1);         // LDS cursor
        if (pos < CAP)                            // OOB insurance (never expected)
            meta[b * CAP + pos] = make_int2(e, (s << 7) | (d & 127));
    }
}

// ================= bucket accumulation (recompute ew; ea is L3-hot) =========
// MODE 0: deg pass  -> fused dinv epilogue (rsqrt of deg+1)
// MODE 1: acc[dst] += ew * p[src], plain store epilogue
// 512 threads = 8 waves/block; LDS 16KB -> 4 blocks/CU target occupancy.
template<int MODE>
__global__ __launch_bounds__(512)
void k_bucket(const float* __restrict__ ea, const int2* __restrict__ meta,
              const int* __restrict__ gcount, const float* __restrict__ We,
              const float* __restrict__ be, const float* __restrict__ p,
              float* __restrict__ outv)
{
    __shared__ double accS[RB * 16];              // 16 KB
    const int tid = threadIdx.x;
    const int b   = blockIdx.x;
    for (int t = tid; t < RB * 16; t += 512) accS[t] = 0.0;

    const int c4 = tid & 3;
    float4 wc[16];
    const float4* We4 = (const float4*)We;
#pragma unroll
    for (int k = 0; k < 16; ++k) wc[k] = We4[k * 4 + c4];
    const float4 bev = ((const float4*)be)[c4];
    const int cnt = min(gcount[b], CAP);
    const int2* ml = meta + b * CAP;
    const float4* ea4 = (const float4*)ea;
    const float4* p4  = (const float4*)p;
    __syncthreads();

#pragma unroll 2
    for (int i = tid >> 2; i < cnt; i += 128) {
        int2 m = ml[i];                           // quad shares 8B -> broadcast
        float4 a = ea4[m.x * 4 + c4];             // random 64B granule, L3-hot (ea=205MB<256MB LLC)
        float4 pv;
        if (MODE == 1) pv = p4[((unsigned)m.y >> 7) * 4 + c4];  // p is 6.4MB, L2-hot
        const int dl = m.y & 127;
        float4 ew = bev;
        ew = ewstep<0>(a, wc, ew);
        ew = ewstep<1>(a, wc, ew);
        ew = ewstep<2>(a, wc, ew);
        ew = ewstep<3>(a, wc, ew);
        if (MODE == 1) {
            accum4(accS, dl, c4,
                   (double)(ew.x * pv.x), (double)(ew.y * pv.y),
                   (double)(ew.z * pv.z), (double)(ew.w * pv.w));
        } else {
            accum4(accS, dl, c4, (double)ew.x, (double)ew.y, (double)ew.z, (double)ew.w);
        }
    }
    __syncthreads();

    // epilogue: unswizzle; MODE 0 additionally applies deg->dinv (self loop +1)
    for (int t = tid; t < RB * 4; t += 512) {
        int nl = t >> 2;
        int ng = b * RB + nl;
        if (ng < N_NODES) {
            const double* s = accS + nl * 16;
            const int pb = ((t & 3) * 4 + nl) & 15;
            float4 o;
            if (MODE == 0) {
                float d0 = (float)s[(pb + 0) & 15] + 1.0f; o.x = (d0 > 0.f) ? rsqrtf(d0 + 1e-12f) : 0.f;
                float d1 = (float)s[(pb + 1) & 15] + 1.0f; o.y = (d1 > 0.f) ? rsqrtf(d1 + 1e-12f) : 0.f;
                float d2 = (float)s[(pb + 2) & 15] + 1.0f; o.z = (d2 > 0.f) ? rsqrtf(d2 + 1e-12f) : 0.f;
                float d3 = (float)s[(pb + 3) & 15] + 1.0f; o.w = (d3 > 0.f) ? rsqrtf(d3 + 1e-12f) : 0.f;
            } else {
                o.x = (float)s[(pb + 0) & 15];
                o.y = (float)s[(pb + 1) & 15];
                o.z = (float)s[(pb + 2) & 15];
                o.w = (float)s[(pb + 3) & 15];
            }
            ((float4*)outv)[ng * 4 + (t & 3)] = o;
        }
    }
}

// ---------------- p = dinv * (x @ W1) ----------------
__global__ __launch_bounds__(256)
void k_xw1(const float* __restrict__ x, const float* __restrict__ W1,
           const float* __restrict__ dinv, float* __restrict__ p)
{
    __shared__ float4 w1s[512];               // [k][c4], k=0..127
    const int t = threadIdx.x;
    const float4* W14 = (const float4*)W1;
    w1s[t]       = W14[t];
    w1s[t + 256] = W14[t + 256];
    __syncthreads();

    const int c4 = t & 3;
    const int nl = t >> 2;                    // 0..63
    const int nb = blockIdx.x * 256;
    int node[4];
    float4 acc[4];
#pragma unroll
    for (int i = 0; i < 4; ++i) {
        node[i] = nb + i * 64 + nl;
        acc[i]  = make_float4(0.f, 0.f, 0.f, 0.f);
    }
    const float4* x4 = (const float4*)x;

    for (int k4 = 0; k4 < 32; ++k4) {
        float4 wv0 = w1s[(k4 * 4 + 0) * 4 + c4];
        float4 wv1 = w1s[(k4 * 4 + 1) * 4 + c4];
        float4 wv2 = w1s[(k4 * 4 + 2) * 4 + c4];
        float4 wv3 = w1s[(k4 * 4 + 3) * 4 + c4];
#pragma unroll
        for (int i = 0; i < 4; ++i) {
            int nn = node[i] < N_NODES ? node[i] : (N_NODES - 1);
            float4 xv = x4[nn * 32 + k4];
            acc[i] = v4fma(xv.x, wv0, acc[i]);
            acc[i] = v4fma(xv.y, wv1, acc[i]);
            acc[i] = v4fma(xv.z, wv2, acc[i]);
            acc[i] = v4fma(xv.w, wv3, acc[i]);
        }
    }
    const float4* dinv4 = (const float4*)dinv;
    float4* pp = (float4*)p;
#pragma unroll
    for (int i = 0; i < 4; ++i) {
        if (node[i] < N_NODES) {
            float4 dv = dinv4[node[i] * 4 + c4];
            float4 o;
            o.x = dv.x * acc[i].x; o.y = dv.y * acc[i].y;
            o.z = dv.z * acc[i].z; o.w = dv.w * acc[i].w;
            pp[node[i] * 4 + c4] = o;
        }
    }
}

// ---------------- conv1 epilogue + h1@W2 + make p2 (in place over p) ----------------
__global__ __launch_bounds__(256)
void k_mid(const float* __restrict__ accA, const float* __restrict__ dinv,
           const float* __restrict__ W2, const float* __restrict__ b1,
           float* __restrict__ p)
{
    const int tid = blockIdx.x * 256 + threadIdx.x;
    const int q   = tid >> 2;                 // node
    if (q >= N_NODES) return;
    const int c4 = threadIdx.x & 3;

    float4 wc[16];
    const float4* W24 = (const float4*)W2;
#pragma unroll
    for (int k = 0; k < 16; ++k) wc[k] = W24[k * 4 + c4];
    const float4 b1v = ((const float4*)b1)[c4];

    const float4 av = ((const float4*)accA)[q * 4 + c4];
    const float4 pv = ((const float4*)p)[q * 4 + c4];
    const float4 dv = ((const float4*)dinv)[q * 4 + c4];

    float4 h1;
    h1.x = fmaxf(fmaf(dv.x, av.x + pv.x, b1v.x), 0.f);
    h1.y = fmaxf(fmaf(dv.y, av.y + pv.y, b1v.y), 0.f);
    h1.z = fmaxf(fmaf(dv.z, av.z + pv.z, b1v.z), 0.f);
    h1.w = fmaxf(fmaf(dv.w, av.w + pv.w, b1v.w), 0.f);

    float4 h2 = make_float4(0.f, 0.f, 0.f, 0.f);
    h2 = ewstep<0>(h1, wc, h2);
    h2 = ewstep<1>(h1, wc, h2);
    h2 = ewstep<2>(h1, wc, h2);
    h2 = ewstep<3>(h1, wc, h2);

    float4 o;
    o.x = dv.x * h2.x; o.y = dv.y * h2.y;
    o.z = dv.z * h2.z; o.w = dv.w * h2.w;
    ((float4*)p)[q * 4 + c4] = o;
}

// ---------------- final epilogue: out = dinv*(acc2 + p2) + b2 ----------------
__global__ __launch_bounds__(256)
void k_out(const float* __restrict__ accB, const float* __restrict__ dinv,
           const float* __restrict__ p, const float* __restrict__ b2,
           float* __restrict__ out)
{
    const int tid = blockIdx.x * 256 + threadIdx.x;
    const int q   = tid >> 2;
    if (q >= N_NODES) return;
    const int c4 = threadIdx.x & 3;
    const float4 b2v = ((const float4*)b2)[c4];
    const float4 av = ((const float4*)accB)[q * 4 + c4];
    const float4 pv = ((const float4*)p)[q * 4 + c4];
    const float4 dv = ((const float4*)dinv)[q * 4 + c4];
    float4 o;
    o.x = fmaf(dv.x, av.x + pv.x, b2v.x);
    o.y = fmaf(dv.y, av.y + pv.y, b2v.y);
    o.z = fmaf(dv.z, av.z + pv.z, b2v.z);
    o.w = fmaf(dv.w, av.w + pv.w, b2v.w);
    ((float4*)out)[q * 4 + c4] = o;
}

extern "C" void kernel_launch(void* const* d_in, const int* in_sizes, int n_in,
                              void* d_out, int out_size, void* d_ws, size_t ws_size,
                              hipStream_t stream)
{
    const float* x   = (const float*)d_in[0];
    const int*   ei  = (const int*)d_in[1];
    const float* ea  = (const float*)d_in[2];
    const float* We  = (const float*)d_in[3];
    const float* be  = (const float*)d_in[4];
    const float* W1  = (const float*)d_in[5];
    const float* b1  = (const float*)d_in[6];
    const float* W2  = (const float*)d_in[7];
    const float* b2  = (const float*)d_in[8];
    float* out = (float*)d_out;

    const int* srcI = ei;
    const int* dstI = ei + N_EDGES;

    // workspace carve (~56 MB; ws proven >=281MB in rounds 2-3)
    float* dinv = (float*)d_ws;          // dinv (fused into deg pass)  (6.4 MB)
    float* p    = dinv + NC16;           // p1 -> p2 in place           (6.4 MB)
    float* accA = p + NC16;              //                             (6.4 MB)
    float* accB = accA + NC16;           //                             (6.4 MB)
    int2*  meta = (int2*)(accB + NC16);  // NB*CAP*8B                   (30.0 MB)
    int*   gcount = (int*)(meta + (size_t)NB * CAP);  // NB ints

    const dim3 blk(256);
    hipLaunchKernelGGL(k_zero, dim3((NB + 255) / 256), blk, 0, stream, gcount);
    hipLaunchKernelGGL(k_part, dim3(NPB), dim3(1024), 0, stream,
                       srcI, dstI, gcount, meta);
    hipLaunchKernelGGL((k_bucket<0>), dim3(NB), dim3(512), 0, stream,
                       ea, meta, gcount, We, be, (const float*)nullptr, dinv);
    hipLaunchKernelGGL(k_xw1, dim3((N_NODES + 255) / 256), blk, 0, stream,
                       x, W1, dinv, p);
    hipLaunchKernelGGL((k_bucket<1>), dim3(NB), dim3(512), 0, stream,
                       ea, meta, gcount, We, be, p, accA);
    hipLaunchKernelGGL(k_mid, dim3((N_NODES * 4 + 255) / 256), blk, 0, stream,
                       accA, dinv, W2, b1, p);
    hipLaunchKernelGGL((k_bucket<1>), dim3(NB), dim3(512), 0, stream,
                       ea, meta, gcount, We, be, p, accB);
    hipLaunchKernelGGL(k_out, dim3((N_NODES * 4 + 255) / 256), blk, 0, stream,
                       accB, dinv, p, b2, out);
}

// Round 5
// 679.474 us; speedup vs baseline: 1.0040x; 1.0040x over previous
//
#include <hip/hip_runtime.h>

static constexpr int N_NODES = 100000;
static constexpr int N_EDGES = 3200000;
static constexpr int NC16    = N_NODES * 16;         // 1.6M
static constexpr int RB      = 128;                  // nodes per bucket
static constexpr int NB      = (N_NODES + RB - 1) / RB;   // 782 buckets
static constexpr int CAP     = 4800;                 // per-bucket cap (mean 4096, +11 sigma)
static constexpr int NPB     = 512;                  // partition blocks
static constexpr int EPB     = N_EDGES / NPB;        // 6250 edges/partition block (exact)

// ---------- small float4 helpers ----------
__device__ __forceinline__ float4 v4fma(float s, float4 w, float4 acc) {
    acc.x = fmaf(s, w.x, acc.x);
    acc.y = fmaf(s, w.y, acc.y);
    acc.z = fmaf(s, w.z, acc.z);
    acc.w = fmaf(s, w.w, acc.w);
    return acc;
}

// broadcast all 4 components from quad-lane KK (v_mov_b32 dpp quad_perm — VALU pipe)
template<int KK>
__device__ __forceinline__ float4 qbcast(float4 a) {
    constexpr int ctrl = KK * 0x55;   // quad_perm:[KK,KK,KK,KK]
    float4 r;
    r.x = __int_as_float(__builtin_amdgcn_mov_dpp(__float_as_int(a.x), ctrl, 0xF, 0xF, true));
    r.y = __int_as_float(__builtin_amdgcn_mov_dpp(__float_as_int(a.y), ctrl, 0xF, 0xF, true));
    r.z = __int_as_float(__builtin_amdgcn_mov_dpp(__float_as_int(a.z), ctrl, 0xF, 0xF, true));
    r.w = __int_as_float(__builtin_amdgcn_mov_dpp(__float_as_int(a.w), ctrl, 0xF, 0xF, true));
    return r;
}

// ew(channels of this lane) += sum over k in [4*KK, 4*KK+4) of a[k] * Wcol[k]
template<int KK>
__device__ __forceinline__ float4 ewstep(float4 a, const float4* wc, float4 ew) {
    float4 v = qbcast<KK>(a);
    ew = v4fma(v.x, wc[4*KK + 0], ew);
    ew = v4fma(v.y, wc[4*KK + 1], ew);
    ew = v4fma(v.z, wc[4*KK + 2], ew);
    ew = v4fma(v.w, wc[4*KK + 3], ew);
    return ew;
}

// Swizzled fp64 LDS accumulate (verified r2-r4): channel c of node dl lives at
// word dl*16 + ((c + dl) & 15) -> lanes spread over all 16 bank-pairs.
__device__ __forceinline__ void accum4(double* __restrict__ accS, int dl, int c4,
                                       double v0, double v1, double v2, double v3) {
    double* row = accS + dl * 16;
    const int pb = (c4 * 4 + dl) & 15;
    atomicAdd(row + ((pb + 0) & 15), v0);
    atomicAdd(row + ((pb + 1) & 15), v1);
    atomicAdd(row + ((pb + 2) & 15), v2);
    atomicAdd(row + ((pb + 3) & 15), v3);
}

// ---------------- zero gcount (kernel, NOT hipMemsetAsync — graph-capture-proof) ----
__global__ __launch_bounds__(256)
void k_zero(int* g) {
    int t = blockIdx.x * 256 + threadIdx.x;
    if (t < NB) g[t] = 0;
}

// =====================================================================
// == PATH A: LDS counting-sort partition + coalesced ew record write ==
// =====================================================================
// r3 lesson: scattering 64B records at random cursors cost 1.42x write
// amplification (310MB) and 182us. Fix: sort the block's 6250 edges by
// bucket in LDS first, then walk the sorted list -> adjacent quads write
// adjacent records (contiguous 1KB runs per wave), and ea is gathered
// within the block's own contiguous 400KB window (L2-resident).
__global__ __launch_bounds__(512)
void k_part_ew(const int* __restrict__ srcI, const int* __restrict__ dstI,
               const float* __restrict__ ea, const float* __restrict__ We,
               const float* __restrict__ be,
               int* __restrict__ gcount,
               float4* __restrict__ ewRec4, int* __restrict__ metaRec)
{
    __shared__ int hist[NB];                  // counts -> local cursor
    __shared__ int lpref[NB];                 // exclusive local prefix
    __shared__ int gbase[NB];                 // global chunk base per bucket
    __shared__ int tsum[512];
    __shared__ int eidS[EPB];                 // edge ids, bucket-sorted
    __shared__ unsigned short bS[EPB];        // bucket per sorted slot
    const int tid = threadIdx.x;
    const int e0  = blockIdx.x * EPB;         // EPB exact: 512*6250 = 3.2M

    for (int t = tid; t < NB; t += 512) hist[t] = 0;
    __syncthreads();
    for (int i = tid; i < EPB; i += 512)
        atomicAdd(&hist[dstI[e0 + i] >> 7], 1);      // LDS int atomic (exact)
    __syncthreads();

    // exclusive prefix scan over hist[0..NB): 2 entries/thread + Hillis-Steele
    int a0 = (2 * tid     < NB) ? hist[2 * tid]     : 0;
    int a1 = (2 * tid + 1 < NB) ? hist[2 * tid + 1] : 0;
    tsum[tid] = a0 + a1;
    __syncthreads();
    for (int off = 1; off < 512; off <<= 1) {
        int v = tsum[tid];
        if (tid >= off) v += tsum[tid - off];
        __syncthreads();
        tsum[tid] = v;
        __syncthreads();
    }
    {
        int ex = tid ? tsum[tid - 1] : 0;
        if (2 * tid     < NB) lpref[2 * tid]     = ex;
        if (2 * tid + 1 < NB) lpref[2 * tid + 1] = ex + a0;
    }
    __syncthreads();

    // reserve global chunks (one atomic per non-empty bucket), reset cursors
    for (int t = tid; t < NB; t += 512) {
        int h = hist[t];
        gbase[t] = (h > 0) ? atomicAdd(&gcount[t], h) : 0;
        hist[t] = 0;
    }
    __syncthreads();

    // scatter into LDS in bucket-sorted order
    for (int i = tid; i < EPB; i += 512) {
        int e = e0 + i;
        int b = dstI[e] >> 7;
        int slot = lpref[b] + atomicAdd(&hist[b], 1);
        eidS[slot] = e;
        bS[slot] = (unsigned short)b;
    }
    __syncthreads();

    // walk sorted list: compute ew, write records coalesced
    const int c4 = tid & 3;
    float4 wc[16];
    const float4* We4 = (const float4*)We;
#pragma unroll
    for (int k = 0; k < 16; ++k) wc[k] = We4[k * 4 + c4];
    const float4 bev = ((const float4*)be)[c4];
    const float4* ea4 = (const float4*)ea;

#pragma unroll 4
    for (int j = tid >> 2; j < EPB; j += 128) {
        int e = eidS[j];
        int b = bS[j];
        int idx = gbase[b] + (j - lpref[b]);      // position within bucket region
        float4 a = ea4[e * 4 + c4];               // gather within block's 400KB window
        float4 ew = bev;
        ew = ewstep<0>(a, wc, ew);
        ew = ewstep<1>(a, wc, ew);
        ew = ewstep<2>(a, wc, ew);
        ew = ewstep<3>(a, wc, ew);
        if (idx < CAP) {                          // OOB insurance (never expected)
            int r = b * CAP + idx;
            ewRec4[r * 4 + c4] = ew;              // adjacent quads -> adjacent 64B
            if (c4 == 0) {
                int s = srcI[e];
                int d = dstI[e];                  // 25KB window, L1-hot
                metaRec[r] = (s << 7) | (d & 127);
            }
        }
    }
}

// ===== stream passes: pure sequential record reads, swizzled LDS f64 acc =====
// MODE 0: deg -> fused dinv epilogue.  MODE 1: acc[dst] += ew * p[src].
// 512 threads, 16KB LDS -> 4 blocks/CU; unroll 4 for MLP.
template<int MODE>
__global__ __launch_bounds__(512)
void k_stream(const float4* __restrict__ ewRec4, const int* __restrict__ metaRec,
              const int* __restrict__ gcount, const float* __restrict__ p,
              float* __restrict__ outv)
{
    __shared__ double accS[RB * 16];              // 16 KB
    const int tid = threadIdx.x;
    const int b   = blockIdx.x;
    for (int t = tid; t < RB * 16; t += 512) accS[t] = 0.0;
    const int c4  = tid & 3;
    const int cnt = min(gcount[b], CAP);
    const int base = b * CAP;
    const float4* p4 = (const float4*)p;
    __syncthreads();

#pragma unroll 4
    for (int i = tid >> 2; i < cnt; i += 128) {
        float4 ew = ewRec4[(base + i) * 4 + c4];  // wave: 1KB contiguous
        int m = metaRec[base + i];
        if (MODE == 1) {
            float4 pv = p4[((unsigned)m >> 7) * 4 + c4];  // p = 6.4MB, L2/L3-hot
            ew.x *= pv.x; ew.y *= pv.y; ew.z *= pv.z; ew.w *= pv.w;
        }
        accum4(accS, m & 127, c4,
               (double)ew.x, (double)ew.y, (double)ew.z, (double)ew.w);
    }
    __syncthreads();

    // epilogue: unswizzle; MODE 0 additionally applies deg->dinv (self loop +1)
    for (int t = tid; t < RB * 4; t += 512) {
        int nl = t >> 2;
        int ng = b * RB + nl;
        if (ng < N_NODES) {
            const double* s = accS + nl * 16;
            const int pb = ((t & 3) * 4 + nl) & 15;
            float4 o;
            if (MODE == 0) {
                float d0 = (float)s[(pb + 0) & 15] + 1.0f; o.x = (d0 > 0.f) ? rsqrtf(d0 + 1e-12f) : 0.f;
                float d1 = (float)s[(pb + 1) & 15] + 1.0f; o.y = (d1 > 0.f) ? rsqrtf(d1 + 1e-12f) : 0.f;
                float d2 = (float)s[(pb + 2) & 15] + 1.0f; o.z = (d2 > 0.f) ? rsqrtf(d2 + 1e-12f) : 0.f;
                float d3 = (float)s[(pb + 3) & 15] + 1.0f; o.w = (d3 > 0.f) ? rsqrtf(d3 + 1e-12f) : 0.f;
            } else {
                o.x = (float)s[(pb + 0) & 15];
                o.y = (float)s[(pb + 1) & 15];
                o.z = (float)s[(pb + 2) & 15];
                o.w = (float)s[(pb + 3) & 15];
            }
            ((float4*)outv)[ng * 4 + (t & 3)] = o;
        }
    }
}

// =====================================================================
// ===== PATH B (fallback if ws too small): r4 recompute pipeline ======
// =====================================================================
__global__ __launch_bounds__(1024)
void k_part(const int* __restrict__ srcI, const int* __restrict__ dstI,
            int* __restrict__ gcount, int2* __restrict__ meta)
{
    __shared__ int hist[NB];
    const int tid  = threadIdx.x;
    const int e0   = blockIdx.x * EPB;
    const int ecnt = min(EPB, N_EDGES - e0);
    for (int t = tid; t < NB; t += 1024) hist[t] = 0;
    __syncthreads();
    for (int i = tid; i < ecnt; i += 1024) {
        int d = dstI[e0 + i];
        atomicAdd(&hist[d >> 7], 1);
    }
    __syncthreads();
    for (int t = tid; t < NB; t += 1024) {
        int h = hist[t];
        hist[t] = (h > 0) ? atomicAdd(&gcount[t], h) : 0;
    }
    __syncthreads();
    for (int i = tid; i < ecnt; i += 1024) {
        int e = e0 + i;
        int d = dstI[e];
        int s = srcI[e];
        int b = d >> 7;
        int pos = atomicAdd(&hist[b], 1);
        if (pos < CAP)
            meta[b * CAP + pos] = make_int2(e, (s << 7) | (d & 127));
    }
}

template<int MODE>
__global__ __launch_bounds__(512)
void k_bucket(const float* __restrict__ ea, const int2* __restrict__ meta,
              const int* __restrict__ gcount, const float* __restrict__ We,
              const float* __restrict__ be, const float* __restrict__ p,
              float* __restrict__ outv)
{
    __shared__ double accS[RB * 16];
    const int tid = threadIdx.x;
    const int b   = blockIdx.x;
    for (int t = tid; t < RB * 16; t += 512) accS[t] = 0.0;

    const int c4 = tid & 3;
    float4 wc[16];
    const float4* We4 = (const float4*)We;
#pragma unroll
    for (int k = 0; k < 16; ++k) wc[k] = We4[k * 4 + c4];
    const float4 bev = ((const float4*)be)[c4];
    const int cnt = min(gcount[b], CAP);
    const int2* ml = meta + b * CAP;
    const float4* ea4 = (const float4*)ea;
    const float4* p4  = (const float4*)p;
    __syncthreads();

#pragma unroll 2
    for (int i = tid >> 2; i < cnt; i += 128) {
        int2 m = ml[i];
        float4 a = ea4[m.x * 4 + c4];
        float4 pv;
        if (MODE == 1) pv = p4[((unsigned)m.y >> 7) * 4 + c4];
        const int dl = m.y & 127;
        float4 ew = bev;
        ew = ewstep<0>(a, wc, ew);
        ew = ewstep<1>(a, wc, ew);
        ew = ewstep<2>(a, wc, ew);
        ew = ewstep<3>(a, wc, ew);
        if (MODE == 1) {
            accum4(accS, dl, c4,
                   (double)(ew.x * pv.x), (double)(ew.y * pv.y),
                   (double)(ew.z * pv.z), (double)(ew.w * pv.w));
        } else {
            accum4(accS, dl, c4, (double)ew.x, (double)ew.y, (double)ew.z, (double)ew.w);
        }
    }
    __syncthreads();

    for (int t = tid; t < RB * 4; t += 512) {
        int nl = t >> 2;
        int ng = b * RB + nl;
        if (ng < N_NODES) {
            const double* s = accS + nl * 16;
            const int pb = ((t & 3) * 4 + nl) & 15;
            float4 o;
            if (MODE == 0) {
                float d0 = (float)s[(pb + 0) & 15] + 1.0f; o.x = (d0 > 0.f) ? rsqrtf(d0 + 1e-12f) : 0.f;
                float d1 = (float)s[(pb + 1) & 15] + 1.0f; o.y = (d1 > 0.f) ? rsqrtf(d1 + 1e-12f) : 0.f;
                float d2 = (float)s[(pb + 2) & 15] + 1.0f; o.z = (d2 > 0.f) ? rsqrtf(d2 + 1e-12f) : 0.f;
                float d3 = (float)s[(pb + 3) & 15] + 1.0f; o.w = (d3 > 0.f) ? rsqrtf(d3 + 1e-12f) : 0.f;
            } else {
                o.x = (float)s[(pb + 0) & 15];
                o.y = (float)s[(pb + 1) & 15];
                o.z = (float)s[(pb + 2) & 15];
                o.w = (float)s[(pb + 3) & 15];
            }
            ((float4*)outv)[ng * 4 + (t & 3)] = o;
        }
    }
}

// =====================================================================
// ===================== shared dense kernels ==========================
// =====================================================================
__global__ __launch_bounds__(256)
void k_xw1(const float* __restrict__ x, const float* __restrict__ W1,
           const float* __restrict__ dinv, float* __restrict__ p)
{
    __shared__ float4 w1s[512];               // [k][c4], k=0..127
    const int t = threadIdx.x;
    const float4* W14 = (const float4*)W1;
    w1s[t]       = W14[t];
    w1s[t + 256] = W14[t + 256];
    __syncthreads();

    const int c4 = t & 3;
    const int nl = t >> 2;                    // 0..63
    const int nb = blockIdx.x * 256;
    int node[4];
    float4 acc[4];
#pragma unroll
    for (int i = 0; i < 4; ++i) {
        node[i] = nb + i * 64 + nl;
        acc[i]  = make_float4(0.f, 0.f, 0.f, 0.f);
    }
    const float4* x4 = (const float4*)x;

    for (int k4 = 0; k4 < 32; ++k4) {
        float4 wv0 = w1s[(k4 * 4 + 0) * 4 + c4];
        float4 wv1 = w1s[(k4 * 4 + 1) * 4 + c4];
        float4 wv2 = w1s[(k4 * 4 + 2) * 4 + c4];
        float4 wv3 = w1s[(k4 * 4 + 3) * 4 + c4];
#pragma unroll
        for (int i = 0; i < 4; ++i) {
            int nn = node[i] < N_NODES ? node[i] : (N_NODES - 1);
            float4 xv = x4[nn * 32 + k4];
            acc[i] = v4fma(xv.x, wv0, acc[i]);
            acc[i] = v4fma(xv.y, wv1, acc[i]);
            acc[i] = v4fma(xv.z, wv2, acc[i]);
            acc[i] = v4fma(xv.w, wv3, acc[i]);
        }
    }
    const float4* dinv4 = (const float4*)dinv;
    float4* pp = (float4*)p;
#pragma unroll
    for (int i = 0; i < 4; ++i) {
        if (node[i] < N_NODES) {
            float4 dv = dinv4[node[i] * 4 + c4];
            float4 o;
            o.x = dv.x * acc[i].x; o.y = dv.y * acc[i].y;
            o.z = dv.z * acc[i].z; o.w = dv.w * acc[i].w;
            pp[node[i] * 4 + c4] = o;
        }
    }
}

__global__ __launch_bounds__(256)
void k_mid(const float* __restrict__ accA, const float* __restrict__ dinv,
           const float* __restrict__ W2, const float* __restrict__ b1,
           float* __restrict__ p)
{
    const int tid = blockIdx.x * 256 + threadIdx.x;
    const int q   = tid >> 2;                 // node
    if (q >= N_NODES) return;
    const int c4 = threadIdx.x & 3;

    float4 wc[16];
    const float4* W24 = (const float4*)W2;
#pragma unroll
    for (int k = 0; k < 16; ++k) wc[k] = W24[k * 4 + c4];
    const float4 b1v = ((const float4*)b1)[c4];

    const float4 av = ((const float4*)accA)[q * 4 + c4];
    const float4 pv = ((const float4*)p)[q * 4 + c4];
    const float4 dv = ((const float4*)dinv)[q * 4 + c4];

    float4 h1;
    h1.x = fmaxf(fmaf(dv.x, av.x + pv.x, b1v.x), 0.f);
    h1.y = fmaxf(fmaf(dv.y, av.y + pv.y, b1v.y), 0.f);
    h1.z = fmaxf(fmaf(dv.z, av.z + pv.z, b1v.z), 0.f);
    h1.w = fmaxf(fmaf(dv.w, av.w + pv.w, b1v.w), 0.f);

    float4 h2 = make_float4(0.f, 0.f, 0.f, 0.f);
    h2 = ewstep<0>(h1, wc, h2);
    h2 = ewstep<1>(h1, wc, h2);
    h2 = ewstep<2>(h1, wc, h2);
    h2 = ewstep<3>(h1, wc, h2);

    float4 o;
    o.x = dv.x * h2.x; o.y = dv.y * h2.y;
    o.z = dv.z * h2.z; o.w = dv.w * h2.w;
    ((float4*)p)[q * 4 + c4] = o;
}

__global__ __launch_bounds__(256)
void k_out(const float* __restrict__ accB, const float* __restrict__ dinv,
           const float* __restrict__ p, const float* __restrict__ b2,
           float* __restrict__ out)
{
    const int tid = blockIdx.x * 256 + threadIdx.x;
    const int q   = tid >> 2;
    if (q >= N_NODES) return;
    const int c4 = threadIdx.x & 3;
    const float4 b2v = ((const float4*)b2)[c4];
    const float4 av = ((const float4*)accB)[q * 4 + c4];
    const float4 pv = ((const float4*)p)[q * 4 + c4];
    const float4 dv = ((const float4*)dinv)[q * 4 + c4];
    float4 o;
    o.x = fmaf(dv.x, av.x + pv.x, b2v.x);
    o.y = fmaf(dv.y, av.y + pv.y, b2v.y);
    o.z = fmaf(dv.z, av.z + pv.z, b2v.z);
    o.w = fmaf(dv.w, av.w + pv.w, b2v.w);
    ((float4*)out)[q * 4 + c4] = o;
}

extern "C" void kernel_launch(void* const* d_in, const int* in_sizes, int n_in,
                              void* d_out, int out_size, void* d_ws, size_t ws_size,
                              hipStream_t stream)
{
    const float* x   = (const float*)d_in[0];
    const int*   ei  = (const int*)d_in[1];
    const float* ea  = (const float*)d_in[2];
    const float* We  = (const float*)d_in[3];
    const float* be  = (const float*)d_in[4];
    const float* W1  = (const float*)d_in[5];
    const float* b1  = (const float*)d_in[6];
    const float* W2  = (const float*)d_in[7];
    const float* b2  = (const float*)d_in[8];
    float* out = (float*)d_out;

    const int* srcI = ei;
    const int* dstI = ei + N_EDGES;

    // common carve (25.6 MB)
    float* dinv = (float*)d_ws;          // dinv (fused into deg pass)  (6.4 MB)
    float* p    = dinv + NC16;           // p1 -> p2 in place           (6.4 MB)
    float* accA = p + NC16;              //                             (6.4 MB)
    float* accB = accA + NC16;           //                             (6.4 MB)

    // PATH A needs: common + NB*CAP*(64+4) + NB*4  ~= 281 MB (proven fits, r2/r3)
    const size_t needA = (size_t)4 * NC16 * 4
                       + (size_t)NB * CAP * (sizeof(float4) * 4 + sizeof(int))
                       + (size_t)NB * sizeof(int) + 4096;

    const dim3 blk(256);

    if (ws_size >= needA) {
        float4* ewRec4 = (float4*)(accB + NC16);                 // NB*CAP*64B (240 MB)
        int*    metaRec = (int*)(ewRec4 + (size_t)NB * CAP * 4); // NB*CAP*4B  (15 MB)
        int*    gcount  = metaRec + (size_t)NB * CAP;            // NB ints

        hipLaunchKernelGGL(k_zero, dim3((NB + 255) / 256), blk, 0, stream, gcount);
        hipLaunchKernelGGL(k_part_ew, dim3(NPB), dim3(512), 0, stream,
                           srcI, dstI, ea, We, be, gcount, ewRec4, metaRec);
        hipLaunchKernelGGL((k_stream<0>), dim3(NB), dim3(512), 0, stream,
                           ewRec4, metaRec, gcount, (const float*)nullptr, dinv);
        hipLaunchKernelGGL(k_xw1, dim3((N_NODES + 255) / 256), blk, 0, stream,
                           x, W1, dinv, p);
        hipLaunchKernelGGL((k_stream<1>), dim3(NB), dim3(512), 0, stream,
                           ewRec4, metaRec, gcount, p, accA);
        hipLaunchKernelGGL(k_mid, dim3((N_NODES * 4 + 255) / 256), blk, 0, stream,
                           accA, dinv, W2, b1, p);
        hipLaunchKernelGGL((k_stream<1>), dim3(NB), dim3(512), 0, stream,
                           ewRec4, metaRec, gcount, p, accB);
        hipLaunchKernelGGL(k_out, dim3((N_NODES * 4 + 255) / 256), blk, 0, stream,
                           accB, dinv, p, b2, out);
    } else {
        // fallback: r4 recompute pipeline (56 MB)
        int2* meta   = (int2*)(accB + NC16);                     // NB*CAP*8B (30 MB)
        int*  gcount = (int*)(meta + (size_t)NB * CAP);          // NB ints

        hipLaunchKernelGGL(k_zero, dim3((NB + 255) / 256), blk, 0, stream, gcount);
        hipLaunchKernelGGL(k_part, dim3(NPB), dim3(1024), 0, stream,
                           srcI, dstI, gcount, meta);
        hipLaunchKernelGGL((k_bucket<0>), dim3(NB), dim3(512), 0, stream,
                           ea, meta, gcount, We, be, (const float*)nullptr, dinv);
        hipLaunchKernelGGL(k_xw1, dim3((N_NODES + 255) / 256), blk, 0, stream,
                           x, W1, dinv, p);
        hipLaunchKernelGGL((k_bucket<1>), dim3(NB), dim3(512), 0, stream,
                           ea, meta, gcount, We, be, p, accA);
        hipLaunchKernelGGL(k_mid, dim3((N_NODES * 4 + 255) / 256), blk, 0, stream,
                           accA, dinv, W2, b1, p);
        hipLaunchKernelGGL((k_bucket<1>), dim3(NB), dim3(512), 0, stream,
                           ea, meta, gcount, We, be, p, accB);
        hipLaunchKernelGGL(k_out, dim3((N_NODES * 4 + 255) / 256), blk, 0, stream,
                           accB, dinv, p, b2, out);
    }
}